// Round 6
// baseline (629.765 us; speedup 1.0000x reference)
//
#include <hip/hip_runtime.h>
#include <hip/hip_bf16.h>

// Problem constants (from reference)
#define TT 128   // time points
#define DD 64    // state dim
#define HH 256   // f-net hidden
#define HK 128   // kernel-net hidden
#define JH (TT*HK)      // 16384 contraction dim for row dot
#define HD (HK*DD)      // 8192

// ---------------------------------------------------------------------------
// k_prep: blocks [0,1024):    A[i, j*HK+h] = w(i,j)*tanh(t_i*Wk1[0,h]+t_j*Wk1[1,h]+bk1[h])
//         blocks [1024,1280): Wk2t[e*HD + h*DD + d] = Wk2[h, d*DD + e]
// ---------------------------------------------------------------------------
__global__ void __launch_bounds__(256)
k_prep(const float* __restrict__ t, const float* __restrict__ Wk1,
       const float* __restrict__ bk1, const float* __restrict__ Wk2,
       float* __restrict__ A, float* __restrict__ Wk2t) {
    __shared__ float tile[32][65];
    int b = blockIdx.x, tid = threadIdx.x;
    if (b < 1024) {
        float dt = t[1] - t[0];
        #pragma unroll
        for (int k = 0; k < 8; ++k) {
            int idx = b * 2048 + k * 256 + tid;
            int h = idx & 127, j = (idx >> 7) & 127, i = idx >> 14;
            float w = (i == 0 || j > i) ? 0.f : dt * ((j == 0 || j == i) ? 0.5f : 1.0f);
            float v = tanhf(t[i] * Wk1[h] + t[j] * Wk1[HK + h] + bk1[h]);
            A[idx] = w * v;
        }
    } else {
        int bb = b - 1024;
        int h = bb >> 1, dh = (bb & 1) * 32;
        for (int k = tid; k < 32 * 64; k += 256) {
            int d = k >> 6, e = k & 63;
            tile[d][e] = Wk2[(size_t)h * (DD * DD) + (size_t)(dh + d) * DD + e];
        }
        __syncthreads();
        for (int k = tid; k < 64 * 32; k += 256) {
            int e = k >> 5, d = k & 31;
            Wk2t[(size_t)e * HD + h * DD + dh + d] = tile[d][e];
        }
    }
}

// ---------------------------------------------------------------------------
// k_FM: grid (32 hd-chunks, 16 j-chunks of 8), 256 threads.
// Each block: recompute y_j (from G prefix; z0 if it==0) and F_j for its 8 j's
// (batched MLP, 8-way weight reuse), then M[j, hd] = sum_e F[j,e]*Wk2t[e,hd].
// Blocks with bx==0 also write bF[j,d] = sum_e bk2[d*DD+e]*F[j,e].
// F itself never goes to global memory.
// ---------------------------------------------------------------------------
__global__ void __launch_bounds__(256)
k_FM(const float* __restrict__ G, const float* __restrict__ z0,
     const float* __restrict__ t,
     const float* __restrict__ W1, const float* __restrict__ b1,
     const float* __restrict__ W2, const float* __restrict__ b2,
     const float* __restrict__ bk2, const float* __restrict__ Wk2t,
     float* __restrict__ M, float* __restrict__ bF, int it) {
    int bx = blockIdx.x;
    int j0 = blockIdx.y * 8;
    int tid = threadIdx.x, part = tid >> 6, d = tid & 63;
    __shared__ float ys[8][DD];                                   // 2 KB
    __shared__ float hs[8][HH];                                   // 8 KB
    __shared__ float red[4][8][DD];                               // 8 KB
    __shared__ __attribute__((aligned(16))) float Fs[8][DD];      // 2 KB
    float dt = t[1] - t[0];

    // ---- y rows j0..j0+7 ----
    if (it == 0) {
        if (tid < DD) {
            float z = z0[tid];
            #pragma unroll
            for (int r = 0; r < 8; ++r) ys[r][tid] = z;
        }
    } else {
        // S = sum_{jp=1}^{j0-1} G[jp,d], 4-way partial
        float s = 0.f;
        for (int jp = 1 + part; jp < j0; jp += 4) s += G[jp * DD + d];
        red[part][0][d] = s;
        __syncthreads();
        if (part == 0) {
            float g0 = G[d];
            float run = red[0][0][d] + red[1][0][d] + red[2][0][d] + red[3][0][d];
            float base = z0[d];
            #pragma unroll
            for (int r = 0; r < 8; ++r) {
                int j = j0 + r;
                float gj = G[j * DD + d];
                ys[r][d] = (j == 0) ? base
                                    : base + dt * (0.5f * g0 + run + 0.5f * gj);
                if (j > 0) run += gj;
            }
        }
    }
    __syncthreads();

    // ---- MLP layer 1: h = tid, 8 j's, W1 column reused x8 ----
    float acc[8];
    {
        float bb = b1[tid];
        #pragma unroll
        for (int r = 0; r < 8; ++r) acc[r] = bb;
    }
    for (int e = 0; e < DD; ++e) {
        float w1v = W1[e * HH + tid];
        #pragma unroll
        for (int r = 0; r < 8; ++r) acc[r] += ys[r][e] * w1v;
    }
    #pragma unroll
    for (int r = 0; r < 8; ++r) hs[r][tid] = tanhf(acc[r]);
    __syncthreads();

    // ---- MLP layer 2: thread (part,d) over h-slice, W2 reused x8 ----
    {
        float a2[8] = {0.f,0.f,0.f,0.f,0.f,0.f,0.f,0.f};
        for (int h = part * 64; h < part * 64 + 64; ++h) {
            float w2v = W2[h * DD + d];
            #pragma unroll
            for (int r = 0; r < 8; ++r) a2[r] += hs[r][h] * w2v;
        }
        #pragma unroll
        for (int r = 0; r < 8; ++r) red[part][r][d] = a2[r];
    }
    __syncthreads();
    // finalize F rows: thread (part,d) handles r = 2*part, 2*part+1
    {
        #pragma unroll
        for (int rr = 0; rr < 2; ++rr) {
            int r = part * 2 + rr;
            Fs[r][d] = b2[d] + red[0][r][d] + red[1][r][d] +
                       red[2][r][d] + red[3][r][d];
        }
    }
    __syncthreads();

    // ---- bF (only hd-chunk 0 blocks) ----
    if (bx == 0) {
        float a3[8] = {0.f,0.f,0.f,0.f,0.f,0.f,0.f,0.f};
        for (int e = part * 16; e < part * 16 + 16; ++e) {
            float bv = bk2[d * DD + e];
            #pragma unroll
            for (int r = 0; r < 8; ++r) a3[r] += Fs[r][e] * bv;
        }
        #pragma unroll
        for (int r = 0; r < 8; ++r) red[part][r][d] = a3[r];
        __syncthreads();
        #pragma unroll
        for (int rr = 0; rr < 2; ++rr) {
            int r = part * 2 + rr;
            bF[(j0 + r) * DD + d] = red[0][r][d] + red[1][r][d] +
                                    red[2][r][d] + red[3][r][d];
        }
    }

    // ---- M: hd = bx*256 + tid ----
    int hd = bx * 256 + tid;
    float macc[8] = {0.f,0.f,0.f,0.f,0.f,0.f,0.f,0.f};
    const float* Wp = Wk2t + hd;
    for (int e = 0; e < DD; e += 8) {
        float w0 = Wp[(size_t)(e+0) * HD];
        float w1 = Wp[(size_t)(e+1) * HD];
        float w2 = Wp[(size_t)(e+2) * HD];
        float w3 = Wp[(size_t)(e+3) * HD];
        float w4 = Wp[(size_t)(e+4) * HD];
        float w5 = Wp[(size_t)(e+5) * HD];
        float w6 = Wp[(size_t)(e+6) * HD];
        float w7 = Wp[(size_t)(e+7) * HD];
        #pragma unroll
        for (int r = 0; r < 8; ++r) {
            float4 f0 = *(const float4*)&Fs[r][e];
            float4 f1 = *(const float4*)&Fs[r][e + 4];
            macc[r] += f0.x*w0 + f0.y*w1 + f0.z*w2 + f0.w*w3
                     + f1.x*w4 + f1.y*w5 + f1.z*w6 + f1.w*w7;
        }
    }
    #pragma unroll
    for (int r = 0; r < 8; ++r) M[(size_t)(j0 + r) * HD + hd] = macc[r];
}

// ---------------------------------------------------------------------------
// k_G: one block per row i (128 blocks, 256 threads).
// G[i,d] = sum_{jh < (i+1)*HK} A[i,jh]*M[jh,d]  +  dt*trap(bF[0..i])[d]
// Pure overwrite of G — no atomics, no combine pass.
// ---------------------------------------------------------------------------
__global__ void __launch_bounds__(256)
k_G(const float* __restrict__ A, const float* __restrict__ M,
    const float* __restrict__ bF, const float* __restrict__ t,
    float* __restrict__ G) {
    int i = blockIdx.x, tid = threadIdx.x;
    int sub = tid >> 6, d = tid & 63;
    __shared__ float red[4][64];
    float dt = t[1] - t[0];

    int Q = (i + 1) * (HK / 4);          // per-sub jh count, multiple of 32
    const float* Arow = A + (size_t)i * JH;
    float acc = 0.f;
    int jh0 = sub * Q;
    for (int jj = jh0; jj < jh0 + Q; jj += 8) {
        float4 a0 = *(const float4*)(Arow + jj);
        float4 a1 = *(const float4*)(Arow + jj + 4);
        const float* Mb = M + (size_t)jj * DD + d;
        float m0 = Mb[0 * DD];
        float m1 = Mb[1 * DD];
        float m2 = Mb[2 * DD];
        float m3 = Mb[3 * DD];
        float m4 = Mb[4 * DD];
        float m5 = Mb[5 * DD];
        float m6 = Mb[6 * DD];
        float m7 = Mb[7 * DD];
        acc += a0.x*m0 + a0.y*m1 + a0.z*m2 + a0.w*m3
             + a1.x*m4 + a1.y*m5 + a1.z*m6 + a1.w*m7;
    }
    // bF trapezoid term (partitioned over sub like the main sum)
    if (i > 0) {
        float s = 0.f;
        for (int jp = sub; jp <= i; jp += 4) {
            float w = (jp == 0 || jp == i) ? 0.5f : 1.0f;
            s += w * bF[jp * DD + d];
        }
        acc += dt * s;
    }
    red[sub][d] = acc;
    __syncthreads();
    if (sub == 0)
        G[i * DD + d] = red[0][d] + red[1][d] + red[2][d] + red[3][d];
}

// ---------------------------------------------------------------------------
// k_out: out[d] = z0[d] + dt * trap(G[0..T-1], d)
// ---------------------------------------------------------------------------
__global__ void __launch_bounds__(256)
k_out(const float* __restrict__ G, const float* __restrict__ z0,
      const float* __restrict__ t, float* __restrict__ out) {
    int tid = threadIdx.x, part = tid >> 6, d = tid & 63;
    __shared__ float red[4][64];
    float dt = t[1] - t[0];
    float s = 0.f;
    for (int j = part; j < TT; j += 4) {
        float w = (j == 0 || j == TT - 1) ? 0.5f : 1.0f;
        s += w * G[j * DD + d];
    }
    red[part][d] = s;
    __syncthreads();
    if (part == 0)
        out[d] = z0[d] + dt * (red[0][d] + red[1][d] + red[2][d] + red[3][d]);
}

extern "C" void kernel_launch(void* const* d_in, const int* in_sizes, int n_in,
                              void* d_out, int out_size, void* d_ws, size_t ws_size,
                              hipStream_t stream) {
    const float* z0  = (const float*)d_in[0];
    const float* t   = (const float*)d_in[1];
    const float* W1  = (const float*)d_in[2];
    const float* b1  = (const float*)d_in[3];
    const float* W2  = (const float*)d_in[4];
    const float* b2  = (const float*)d_in[5];
    const float* Wk1 = (const float*)d_in[6];
    const float* bk1 = (const float*)d_in[7];
    const float* Wk2 = (const float*)d_in[8];
    const float* bk2 = (const float*)d_in[9];
    float* out = (float*)d_out;

    float* ws   = (float*)d_ws;
    float* A    = ws;                       // T*T*HK   = 2,097,152
    float* Wk2t = A    + (size_t)TT*TT*HK;  // HK*D*D   =   524,288
    float* M    = Wk2t + (size_t)HK*DD*DD;  // T*HK*D   = 1,048,576
    float* bF   = M    + (size_t)TT*HK*DD;  // T*D
    float* G    = bF   + TT*DD;             // T*D

    // 1: A + Wk2t
    k_prep<<<1280, 256, 0, stream>>>(t, Wk1, bk1, Wk2, A, Wk2t);

    // 2-7: three fixed-point iterations, 2 launches each
    for (int it = 0; it < 3; ++it) {
        k_FM<<<dim3(32, 16), 256, 0, stream>>>(G, z0, t, W1, b1, W2, b2,
                                               bk2, Wk2t, M, bF, it);
        k_G<<<TT, 256, 0, stream>>>(A, M, bF, t, G);
    }
    // 8: output
    k_out<<<1, 256, 0, stream>>>(G, z0, t, out);
}

// Round 7
// 493.863 us; speedup vs baseline: 1.2752x; 1.2752x over previous
//
#include <hip/hip_runtime.h>
#include <hip/hip_bf16.h>

// Problem constants (from reference)
#define TT 128   // time points
#define DD 64    // state dim
#define HH 256   // f-net hidden
#define HK 128   // kernel-net hidden
#define JH (TT*HK)      // 16384 contraction dim
#define HD (HK*DD)      // 8192
#define NCHUNK 64       // jh chunks of 256 (= 2 j's each)

// ---------------------------------------------------------------------------
// k_prep: blocks [0,1024):    A[i, j*HK+h] = w(i,j)*tanh(t_i*Wk1[0,h]+t_j*Wk1[1,h]+bk1[h])
//         blocks [1024,1280): Wk2t[e*HD + h*DD + d] = Wk2[h, d*DD + e]
//         block 1279 also zeroes the done/gdone counters for this call.
// ---------------------------------------------------------------------------
__global__ void __launch_bounds__(256)
k_prep(const float* __restrict__ t, const float* __restrict__ Wk1,
       const float* __restrict__ bk1, const float* __restrict__ Wk2,
       float* __restrict__ A, float* __restrict__ Wk2t,
       int* __restrict__ counters) {
    __shared__ float tile[32][65];
    int b = blockIdx.x, tid = threadIdx.x;
    if (b < 1024) {
        float dt = t[1] - t[0];
        #pragma unroll
        for (int k = 0; k < 8; ++k) {
            int idx = b * 2048 + k * 256 + tid;
            int h = idx & 127, j = (idx >> 7) & 127, i = idx >> 14;
            float w = (i == 0 || j > i) ? 0.f : dt * ((j == 0 || j == i) ? 0.5f : 1.0f);
            float v = tanhf(t[i] * Wk1[h] + t[j] * Wk1[HK + h] + bk1[h]);
            A[idx] = w * v;
        }
    } else {
        if (b == 1279 && tid < 20) counters[tid] = 0;   // done[16] + gdone
        int bb = b - 1024;
        int h = bb >> 1, dh = (bb & 1) * 32;
        for (int k = tid; k < 32 * 64; k += 256) {
            int d = k >> 6, e = k & 63;
            tile[d][e] = Wk2[(size_t)h * (DD * DD) + (size_t)(dh + d) * DD + e];
        }
        __syncthreads();
        for (int k = tid; k < 64 * 32; k += 256) {
            int e = k >> 5, d = k & 31;
            Wk2t[(size_t)e * HD + h * DD + dh + d] = tile[d][e];
        }
    }
}

// ---------------------------------------------------------------------------
// k_FM: grid (32 hd-chunks, 16 j-chunks of 8), 256 threads.
// Each block: recompute y_j (from G prefix; z0 if it==0) and F_j for its 8 j's
// (batched MLP, 8-way weight reuse), then M[j, hd] = sum_e F[j,e]*Wk2t[e,hd].
// Blocks with bx==0 also write bF[j,d] = sum_e bk2[d*DD+e]*F[j,e].
// ---------------------------------------------------------------------------
__global__ void __launch_bounds__(256)
k_FM(const float* __restrict__ G, const float* __restrict__ z0,
     const float* __restrict__ t,
     const float* __restrict__ W1, const float* __restrict__ b1,
     const float* __restrict__ W2, const float* __restrict__ b2,
     const float* __restrict__ bk2, const float* __restrict__ Wk2t,
     float* __restrict__ M, float* __restrict__ bF, int it) {
    int bx = blockIdx.x;
    int j0 = blockIdx.y * 8;
    int tid = threadIdx.x, part = tid >> 6, d = tid & 63;
    __shared__ float ys[8][DD];
    __shared__ float hs[8][HH];
    __shared__ float red[4][8][DD];
    __shared__ __attribute__((aligned(16))) float Fs[8][DD];
    float dt = t[1] - t[0];

    // ---- y rows j0..j0+7 ----
    if (it == 0) {
        if (tid < DD) {
            float z = z0[tid];
            #pragma unroll
            for (int r = 0; r < 8; ++r) ys[r][tid] = z;
        }
    } else {
        float s = 0.f;
        for (int jp = 1 + part; jp < j0; jp += 4) s += G[jp * DD + d];
        red[part][0][d] = s;
        __syncthreads();
        if (part == 0) {
            float g0 = G[d];
            float run = red[0][0][d] + red[1][0][d] + red[2][0][d] + red[3][0][d];
            float base = z0[d];
            #pragma unroll
            for (int r = 0; r < 8; ++r) {
                int j = j0 + r;
                float gj = G[j * DD + d];
                ys[r][d] = (j == 0) ? base
                                    : base + dt * (0.5f * g0 + run + 0.5f * gj);
                if (j > 0) run += gj;
            }
        }
    }
    __syncthreads();

    // ---- MLP layer 1 ----
    float acc[8];
    {
        float bb = b1[tid];
        #pragma unroll
        for (int r = 0; r < 8; ++r) acc[r] = bb;
    }
    for (int e = 0; e < DD; ++e) {
        float w1v = W1[e * HH + tid];
        #pragma unroll
        for (int r = 0; r < 8; ++r) acc[r] += ys[r][e] * w1v;
    }
    #pragma unroll
    for (int r = 0; r < 8; ++r) hs[r][tid] = tanhf(acc[r]);
    __syncthreads();

    // ---- MLP layer 2 ----
    {
        float a2[8] = {0.f,0.f,0.f,0.f,0.f,0.f,0.f,0.f};
        for (int h = part * 64; h < part * 64 + 64; ++h) {
            float w2v = W2[h * DD + d];
            #pragma unroll
            for (int r = 0; r < 8; ++r) a2[r] += hs[r][h] * w2v;
        }
        #pragma unroll
        for (int r = 0; r < 8; ++r) red[part][r][d] = a2[r];
    }
    __syncthreads();
    {
        #pragma unroll
        for (int rr = 0; rr < 2; ++rr) {
            int r = part * 2 + rr;
            Fs[r][d] = b2[d] + red[0][r][d] + red[1][r][d] +
                       red[2][r][d] + red[3][r][d];
        }
    }
    __syncthreads();

    // ---- bF (only hd-chunk 0 blocks) ----
    if (bx == 0) {
        float a3[8] = {0.f,0.f,0.f,0.f,0.f,0.f,0.f,0.f};
        for (int e = part * 16; e < part * 16 + 16; ++e) {
            float bv = bk2[d * DD + e];
            #pragma unroll
            for (int r = 0; r < 8; ++r) a3[r] += Fs[r][e] * bv;
        }
        #pragma unroll
        for (int r = 0; r < 8; ++r) red[part][r][d] = a3[r];
        __syncthreads();
        #pragma unroll
        for (int rr = 0; rr < 2; ++rr) {
            int r = part * 2 + rr;
            bF[(j0 + r) * DD + d] = red[0][r][d] + red[1][r][d] +
                                    red[2][r][d] + red[3][r][d];
        }
    }

    // ---- M ----
    int hd = bx * 256 + tid;
    float macc[8] = {0.f,0.f,0.f,0.f,0.f,0.f,0.f,0.f};
    const float* Wp = Wk2t + hd;
    for (int e = 0; e < DD; e += 8) {
        float w0 = Wp[(size_t)(e+0) * HD];
        float w1 = Wp[(size_t)(e+1) * HD];
        float w2 = Wp[(size_t)(e+2) * HD];
        float w3 = Wp[(size_t)(e+3) * HD];
        float w4 = Wp[(size_t)(e+4) * HD];
        float w5 = Wp[(size_t)(e+5) * HD];
        float w6 = Wp[(size_t)(e+6) * HD];
        float w7 = Wp[(size_t)(e+7) * HD];
        #pragma unroll
        for (int r = 0; r < 8; ++r) {
            float4 f0 = *(const float4*)&Fs[r][e];
            float4 f1 = *(const float4*)&Fs[r][e + 4];
            macc[r] += f0.x*w0 + f0.y*w1 + f0.z*w2 + f0.w*w3
                     + f1.x*w4 + f1.y*w5 + f1.z*w6 + f1.w*w7;
        }
    }
    #pragma unroll
    for (int r = 0; r < 8; ++r) M[(size_t)(j0 + r) * HD + hd] = macc[r];
}

// ---------------------------------------------------------------------------
// k_G: tiled partials + decoupled last-block reduction (no spin, no hot atomics).
// grid (16 itiles of 8 rows, 64 chunks of 256 jh); active iff c <= 4*itile+3.
// Each active block writes P[c][rows][d]; the LAST block of an itile (per
// done[itile] counter) reduces all chunks + bF trapezoid into G rows.
// On final_it, the last of the 16 reducers (gdone) computes out directly.
// ---------------------------------------------------------------------------
__global__ void __launch_bounds__(256)
k_G(const float* __restrict__ A, const float* __restrict__ M,
    const float* __restrict__ bF, const float* __restrict__ t,
    float* __restrict__ P, float* __restrict__ G,
    int* __restrict__ done, int* __restrict__ gdone,
    const float* __restrict__ z0, float* __restrict__ out, int final_it) {
    int itile = blockIdx.x, c = blockIdx.y;
    int nactive = 4 * itile + 4;
    if (c >= nactive) return;
    __shared__ __attribute__((aligned(16))) float As[8 * 256];   // 8 KB
    __shared__ float red[4][8][64];                              // 8 KB
    __shared__ int lastflag;
    int tid = threadIdx.x, sub = tid >> 6, d = tid & 63;
    float dt = t[1] - t[0];

    // ---- stage A tile, compute chunk partials ----
    {
        const float* Ab = A + (size_t)itile * 8 * JH + c * 256;
        float4* As4 = (float4*)As;
        #pragma unroll
        for (int k = 0; k < 2; ++k) {
            int idx = tid + k * 256;
            int r = idx >> 6, q = idx & 63;
            As4[idx] = *(const float4*)(Ab + (size_t)r * JH + q * 4);
        }
    }
    __syncthreads();
    float acc[8] = {0.f,0.f,0.f,0.f,0.f,0.f,0.f,0.f};
    const float* Mp = M + ((size_t)c * 256) * DD + d;
    int jl0 = sub * 64;
    for (int jl = jl0; jl < jl0 + 64; jl += 8) {
        float m0 = Mp[(size_t)(jl + 0) * DD];
        float m1 = Mp[(size_t)(jl + 1) * DD];
        float m2 = Mp[(size_t)(jl + 2) * DD];
        float m3 = Mp[(size_t)(jl + 3) * DD];
        float m4 = Mp[(size_t)(jl + 4) * DD];
        float m5 = Mp[(size_t)(jl + 5) * DD];
        float m6 = Mp[(size_t)(jl + 6) * DD];
        float m7 = Mp[(size_t)(jl + 7) * DD];
        #pragma unroll
        for (int r = 0; r < 8; ++r) {
            float4 a0 = *(const float4*)&As[r * 256 + jl];
            float4 a1 = *(const float4*)&As[r * 256 + jl + 4];
            acc[r] += a0.x*m0 + a0.y*m1 + a0.z*m2 + a0.w*m3
                    + a1.x*m4 + a1.y*m5 + a1.z*m6 + a1.w*m7;
        }
    }
    #pragma unroll
    for (int r = 0; r < 8; ++r) red[sub][r][d] = acc[r];
    __syncthreads();
    if (sub == 0) {
        #pragma unroll
        for (int r = 0; r < 8; ++r) {
            float v = red[0][r][d] + red[1][r][d] + red[2][r][d] + red[3][r][d];
            P[(size_t)c * (TT * DD) + (itile * 8 + r) * DD + d] = v;
        }
    }
    __syncthreads();          // drains vmem (compiler emits vmcnt(0) before barrier)

    // ---- signal; last block reduces ----
    if (tid == 0) {
        __threadfence();      // release: make P visible device-wide
        int old = atomicAdd(&done[itile], 1);
        lastflag = (old == nactive - 1);
        if (lastflag) atomicExch(&done[itile], 0);   // reset for next dispatch
    }
    __syncthreads();
    if (!lastflag) return;
    __threadfence();          // acquire: invalidate stale cached P

    #pragma unroll
    for (int r = 0; r < 8; ++r) {
        int i = itile * 8 + r;
        int cmax = i >> 1;
        float a = 0.f;
        for (int c2 = sub; c2 <= cmax; c2 += 4)
            a += P[(size_t)c2 * (TT * DD) + i * DD + d];
        if (i > 0) {
            float s2 = 0.f;
            for (int jp = sub; jp <= i; jp += 4) {
                float w = (jp == 0 || jp == i) ? 0.5f : 1.0f;
                s2 += w * bF[jp * DD + d];
            }
            a += dt * s2;
        }
        red[sub][r][d] = a;
    }
    __syncthreads();
    if (sub == 0) {
        #pragma unroll
        for (int r = 0; r < 8; ++r) {
            int i = itile * 8 + r;
            G[i * DD + d] = red[0][r][d] + red[1][r][d] +
                            red[2][r][d] + red[3][r][d];
        }
    }

    // ---- final iteration: last reducer computes out ----
    if (final_it) {
        __syncthreads();      // drain G stores
        if (tid == 0) {
            __threadfence();
            int old = atomicAdd(gdone, 1);
            lastflag = (old == 15);
        }
        __syncthreads();
        if (!lastflag) return;
        __threadfence();
        float s = 0.f;
        for (int j = sub; j < TT; j += 4) {
            float w = (j == 0 || j == TT - 1) ? 0.5f : 1.0f;
            s += w * G[j * DD + d];
        }
        red[sub][0][d] = s;
        __syncthreads();
        if (sub == 0)
            out[d] = z0[d] + dt * (red[0][0][d] + red[1][0][d] +
                                   red[2][0][d] + red[3][0][d]);
    }
}

extern "C" void kernel_launch(void* const* d_in, const int* in_sizes, int n_in,
                              void* d_out, int out_size, void* d_ws, size_t ws_size,
                              hipStream_t stream) {
    const float* z0  = (const float*)d_in[0];
    const float* t   = (const float*)d_in[1];
    const float* W1  = (const float*)d_in[2];
    const float* b1  = (const float*)d_in[3];
    const float* W2  = (const float*)d_in[4];
    const float* b2  = (const float*)d_in[5];
    const float* Wk1 = (const float*)d_in[6];
    const float* bk1 = (const float*)d_in[7];
    const float* Wk2 = (const float*)d_in[8];
    const float* bk2 = (const float*)d_in[9];
    float* out = (float*)d_out;

    float* ws   = (float*)d_ws;
    float* A    = ws;                       // T*T*HK   = 2,097,152
    float* Wk2t = A    + (size_t)TT*TT*HK;  // HK*D*D   =   524,288
    float* M    = Wk2t + (size_t)HK*DD*DD;  // T*HK*D   = 1,048,576
    float* bF   = M    + (size_t)TT*HK*DD;  // T*D
    float* G    = bF   + TT*DD;             // T*D
    float* P    = G    + TT*DD;             // NCHUNK*T*D = 524,288
    int*   cnt  = (int*)(P + (size_t)NCHUNK*TT*DD);  // done[16] + gdone
    int*   done  = cnt;
    int*   gdone = cnt + 16;

    // 1: A + Wk2t + zero counters
    k_prep<<<1280, 256, 0, stream>>>(t, Wk1, bk1, Wk2, A, Wk2t, cnt);

    // 2-7: three fixed-point iterations, 2 launches each; out folded into last k_G
    for (int it = 0; it < 3; ++it) {
        k_FM<<<dim3(32, 16), 256, 0, stream>>>(G, z0, t, W1, b1, W2, b2,
                                               bk2, Wk2t, M, bF, it);
        k_G<<<dim3(16, NCHUNK), 256, 0, stream>>>(A, M, bF, t, P, G,
                                                  done, gdone, z0, out,
                                                  (it == 2) ? 1 : 0);
    }
}

// Round 8
// 311.683 us; speedup vs baseline: 2.0205x; 1.5845x over previous
//
#include <hip/hip_runtime.h>
#include <hip/hip_bf16.h>

// Problem constants (from reference)
#define TT 128   // time points
#define DD 64    // state dim
#define HH 256   // f-net hidden
#define HK 128   // kernel-net hidden
#define JH (TT*HK)      // 16384 contraction dim
#define HD (HK*DD)      // 8192
#define NCHUNK 64       // jh chunks of 256 (= 2 j's each)

// ---------------------------------------------------------------------------
// k_prep: blocks [0,1024):    A[i, j*HK+h] = w(i,j)*tanh(t_i*Wk1[0,h]+t_j*Wk1[1,h]+bk1[h])
//         blocks [1024,1280): Wk2t[e*HD + h*DD + d] = Wk2[h, d*DD + e]
// ---------------------------------------------------------------------------
__global__ void __launch_bounds__(256)
k_prep(const float* __restrict__ t, const float* __restrict__ Wk1,
       const float* __restrict__ bk1, const float* __restrict__ Wk2,
       float* __restrict__ A, float* __restrict__ Wk2t) {
    __shared__ float tile[32][65];
    int b = blockIdx.x, tid = threadIdx.x;
    if (b < 1024) {
        float dt = t[1] - t[0];
        #pragma unroll
        for (int k = 0; k < 8; ++k) {
            int idx = b * 2048 + k * 256 + tid;
            int h = idx & 127, j = (idx >> 7) & 127, i = idx >> 14;
            float w = (i == 0 || j > i) ? 0.f : dt * ((j == 0 || j == i) ? 0.5f : 1.0f);
            float v = tanhf(t[i] * Wk1[h] + t[j] * Wk1[HK + h] + bk1[h]);
            A[idx] = w * v;
        }
    } else {
        int bb = b - 1024;
        int h = bb >> 1, dh = (bb & 1) * 32;
        for (int k = tid; k < 32 * 64; k += 256) {
            int d = k >> 6, e = k & 63;
            tile[d][e] = Wk2[(size_t)h * (DD * DD) + (size_t)(dh + d) * DD + e];
        }
        __syncthreads();
        for (int k = tid; k < 64 * 32; k += 256) {
            int e = k >> 5, d = k & 31;
            Wk2t[(size_t)e * HD + h * DD + dh + d] = tile[d][e];
        }
    }
}

// ---------------------------------------------------------------------------
// k_FM: grid (32 hd-chunks, 16 j-chunks of 8), 256 threads.
// Each block: recompute y_j (from G prefix; z0 if it==0) and F_j for its 8 j's
// (batched MLP, 8-way weight reuse), then M[j, hd] = sum_e F[j,e]*Wk2t[e,hd].
// Blocks with bx==0 also write bF[j,d] = sum_e bk2[d*DD+e]*F[j,e].
// ---------------------------------------------------------------------------
__global__ void __launch_bounds__(256)
k_FM(const float* __restrict__ G, const float* __restrict__ z0,
     const float* __restrict__ t,
     const float* __restrict__ W1, const float* __restrict__ b1,
     const float* __restrict__ W2, const float* __restrict__ b2,
     const float* __restrict__ bk2, const float* __restrict__ Wk2t,
     float* __restrict__ M, float* __restrict__ bF, int it) {
    int bx = blockIdx.x;
    int j0 = blockIdx.y * 8;
    int tid = threadIdx.x, part = tid >> 6, d = tid & 63;
    __shared__ float ys[8][DD];
    __shared__ float hs[8][HH];
    __shared__ float red[4][8][DD];
    __shared__ __attribute__((aligned(16))) float Fs[8][DD];
    float dt = t[1] - t[0];

    // ---- y rows j0..j0+7 ----
    if (it == 0) {
        if (tid < DD) {
            float z = z0[tid];
            #pragma unroll
            for (int r = 0; r < 8; ++r) ys[r][tid] = z;
        }
    } else {
        float s = 0.f;
        for (int jp = 1 + part; jp < j0; jp += 4) s += G[jp * DD + d];
        red[part][0][d] = s;
        __syncthreads();
        if (part == 0) {
            float g0 = G[d];
            float run = red[0][0][d] + red[1][0][d] + red[2][0][d] + red[3][0][d];
            float base = z0[d];
            #pragma unroll
            for (int r = 0; r < 8; ++r) {
                int j = j0 + r;
                float gj = G[j * DD + d];
                ys[r][d] = (j == 0) ? base
                                    : base + dt * (0.5f * g0 + run + 0.5f * gj);
                if (j > 0) run += gj;
            }
        }
    }
    __syncthreads();

    // ---- MLP layer 1 ----
    float acc[8];
    {
        float bb = b1[tid];
        #pragma unroll
        for (int r = 0; r < 8; ++r) acc[r] = bb;
    }
    for (int e = 0; e < DD; ++e) {
        float w1v = W1[e * HH + tid];
        #pragma unroll
        for (int r = 0; r < 8; ++r) acc[r] += ys[r][e] * w1v;
    }
    #pragma unroll
    for (int r = 0; r < 8; ++r) hs[r][tid] = tanhf(acc[r]);
    __syncthreads();

    // ---- MLP layer 2 ----
    {
        float a2[8] = {0.f,0.f,0.f,0.f,0.f,0.f,0.f,0.f};
        for (int h = part * 64; h < part * 64 + 64; ++h) {
            float w2v = W2[h * DD + d];
            #pragma unroll
            for (int r = 0; r < 8; ++r) a2[r] += hs[r][h] * w2v;
        }
        #pragma unroll
        for (int r = 0; r < 8; ++r) red[part][r][d] = a2[r];
    }
    __syncthreads();
    {
        #pragma unroll
        for (int rr = 0; rr < 2; ++rr) {
            int r = part * 2 + rr;
            Fs[r][d] = b2[d] + red[0][r][d] + red[1][r][d] +
                       red[2][r][d] + red[3][r][d];
        }
    }
    __syncthreads();

    // ---- bF (only hd-chunk 0 blocks) ----
    if (bx == 0) {
        float a3[8] = {0.f,0.f,0.f,0.f,0.f,0.f,0.f,0.f};
        for (int e = part * 16; e < part * 16 + 16; ++e) {
            float bv = bk2[d * DD + e];
            #pragma unroll
            for (int r = 0; r < 8; ++r) a3[r] += Fs[r][e] * bv;
        }
        #pragma unroll
        for (int r = 0; r < 8; ++r) red[part][r][d] = a3[r];
        __syncthreads();
        #pragma unroll
        for (int rr = 0; rr < 2; ++rr) {
            int r = part * 2 + rr;
            bF[(j0 + r) * DD + d] = red[0][r][d] + red[1][r][d] +
                                    red[2][r][d] + red[3][r][d];
        }
    }

    // ---- M ----
    int hd = bx * 256 + tid;
    float macc[8] = {0.f,0.f,0.f,0.f,0.f,0.f,0.f,0.f};
    const float* Wp = Wk2t + hd;
    for (int e = 0; e < DD; e += 8) {
        float w0 = Wp[(size_t)(e+0) * HD];
        float w1 = Wp[(size_t)(e+1) * HD];
        float w2 = Wp[(size_t)(e+2) * HD];
        float w3 = Wp[(size_t)(e+3) * HD];
        float w4 = Wp[(size_t)(e+4) * HD];
        float w5 = Wp[(size_t)(e+5) * HD];
        float w6 = Wp[(size_t)(e+6) * HD];
        float w7 = Wp[(size_t)(e+7) * HD];
        #pragma unroll
        for (int r = 0; r < 8; ++r) {
            float4 f0 = *(const float4*)&Fs[r][e];
            float4 f1 = *(const float4*)&Fs[r][e + 4];
            macc[r] += f0.x*w0 + f0.y*w1 + f0.z*w2 + f0.w*w3
                     + f1.x*w4 + f1.y*w5 + f1.z*w6 + f1.w*w7;
        }
    }
    #pragma unroll
    for (int r = 0; r < 8; ++r) M[(size_t)(j0 + r) * HD + hd] = macc[r];
}

// ---------------------------------------------------------------------------
// k_G1 (r4-proven): P[c, i, d] = sum_{jh in chunk c (256 wide)} A[i,jh]*M[jh,d]
// grid: (16 itiles of 8 rows, 64 chunks); active iff c <= 4*itile+3 (544 blocks)
// Plain stores only — no atomics, no fences.
// ---------------------------------------------------------------------------
__global__ void __launch_bounds__(256)
k_G1(const float* __restrict__ A, const float* __restrict__ M,
     float* __restrict__ P) {
    int itile = blockIdx.x, c = blockIdx.y;
    if (c > 4 * itile + 3) return;
    __shared__ __attribute__((aligned(16))) float As[8 * 256];   // 8 KB
    __shared__ float red[4][8][64];                              // 8 KB
    int tid = threadIdx.x, sub = tid >> 6, d = tid & 63;
    {
        const float* Ab = A + (size_t)itile * 8 * JH + c * 256;
        float4* As4 = (float4*)As;
        #pragma unroll
        for (int k = 0; k < 2; ++k) {
            int idx = tid + k * 256;          // 512 float4
            int r = idx >> 6, q = idx & 63;
            As4[idx] = *(const float4*)(Ab + (size_t)r * JH + q * 4);
        }
    }
    __syncthreads();
    float acc[8] = {0.f,0.f,0.f,0.f,0.f,0.f,0.f,0.f};
    const float* Mp = M + ((size_t)c * 256) * DD + d;
    int jl0 = sub * 64;
    for (int jl = jl0; jl < jl0 + 64; jl += 8) {
        float m0 = Mp[(size_t)(jl + 0) * DD];
        float m1 = Mp[(size_t)(jl + 1) * DD];
        float m2 = Mp[(size_t)(jl + 2) * DD];
        float m3 = Mp[(size_t)(jl + 3) * DD];
        float m4 = Mp[(size_t)(jl + 4) * DD];
        float m5 = Mp[(size_t)(jl + 5) * DD];
        float m6 = Mp[(size_t)(jl + 6) * DD];
        float m7 = Mp[(size_t)(jl + 7) * DD];
        #pragma unroll
        for (int r = 0; r < 8; ++r) {
            float4 a0 = *(const float4*)&As[r * 256 + jl];
            float4 a1 = *(const float4*)&As[r * 256 + jl + 4];
            acc[r] += a0.x*m0 + a0.y*m1 + a0.z*m2 + a0.w*m3
                    + a1.x*m4 + a1.y*m5 + a1.z*m6 + a1.w*m7;
        }
    }
    #pragma unroll
    for (int r = 0; r < 8; ++r) red[sub][r][d] = acc[r];
    __syncthreads();
    if (sub == 0) {
        #pragma unroll
        for (int r = 0; r < 8; ++r) {
            float v = red[0][r][d] + red[1][r][d] + red[2][r][d] + red[3][r][d];
            P[(size_t)c * (TT * DD) + (itile * 8 + r) * DD + d] = v;
        }
    }
}

// ---------------------------------------------------------------------------
// k_Gfin (r4-proven): G[j,d] = sum_{c<=j>>1} P[c,j,d] + dt * trap(bF[0..j], d)
// ---------------------------------------------------------------------------
__global__ void __launch_bounds__(256)
k_Gfin(const float* __restrict__ P, const float* __restrict__ bF,
       const float* __restrict__ t, float* __restrict__ G) {
    int j = blockIdx.x, tid = threadIdx.x;
    int part = tid >> 6, d = tid & 63;
    __shared__ float red[4][64];
    float dt = t[1] - t[0];
    float a = 0.f;
    int cmax = j >> 1;
    for (int c = part; c <= cmax; c += 4) a += P[(size_t)c * (TT * DD) + j * DD + d];
    if (j > 0) {
        float s = 0.f;
        for (int jp = part; jp <= j; jp += 4) {
            float w = (jp == 0 || jp == j) ? 0.5f : 1.0f;
            s += w * bF[jp * DD + d];
        }
        a += dt * s;
    }
    red[part][d] = a;
    __syncthreads();
    if (part == 0)
        G[j * DD + d] = red[0][d] + red[1][d] + red[2][d] + red[3][d];
}

// ---------------------------------------------------------------------------
// k_outP: out[d] = z0[d] + dt * sum_j w_j * G[j,d], computed directly from
// P partials and bF (skips the final k_Gfin launch). Single block.
//   G[j,d] = B[j,d] + bFt[j,d];  B[j,d] = sum_{c<=j>>1} P[c,j,d]
//   bFt[j,d] = dt*(0.5 bF[0,d] + sum_{0<p<j} bF[p,d] + 0.5 bF[j,d]),  bFt[0]=0
// ---------------------------------------------------------------------------
__global__ void __launch_bounds__(256)
k_outP(const float* __restrict__ P, const float* __restrict__ bF,
       const float* __restrict__ z0, const float* __restrict__ t,
       float* __restrict__ out) {
    __shared__ float bfs[TT][DD];      // 32 KB
    __shared__ float red[4][64];
    int tid = threadIdx.x, part = tid >> 6, d = tid & 63;
    float dt = t[1] - t[0];
    for (int k = tid; k < TT * DD; k += 256) bfs[k >> 6][k & 63] = bF[k];
    __syncthreads();
    // B-term: sum_j w_j * B[j,d], rows strided over part
    float sB = 0.f;
    for (int j = part; j < TT; j += 4) {
        float wj = (j == 0 || j == TT - 1) ? 0.5f : 1.0f;
        int cmax = j >> 1;
        float a = 0.f;
        int c = 0;
        for (; c + 3 <= cmax; c += 4) {
            float p0 = P[(size_t)(c + 0) * (TT * DD) + j * DD + d];
            float p1 = P[(size_t)(c + 1) * (TT * DD) + j * DD + d];
            float p2 = P[(size_t)(c + 2) * (TT * DD) + j * DD + d];
            float p3 = P[(size_t)(c + 3) * (TT * DD) + j * DD + d];
            a += p0 + p1 + p2 + p3;
        }
        for (; c <= cmax; ++c) a += P[(size_t)c * (TT * DD) + j * DD + d];
        sB += wj * a;
    }
    red[part][d] = sB;
    __syncthreads();
    if (part == 0) {
        // bFt-term: running double-prefix over LDS-resident bF
        float run = 0.f, accT = 0.f;
        float b0 = 0.5f * bfs[0][d];
        for (int j = 1; j < TT; ++j) {
            float bj = bfs[j][d];
            float bft = dt * (b0 + run + 0.5f * bj);
            float wj = (j == TT - 1) ? 0.5f : 1.0f;
            accT += wj * bft;
            run += bj;
        }
        float Btot = red[0][d] + red[1][d] + red[2][d] + red[3][d];
        out[d] = z0[d] + dt * (Btot + accT);
    }
}

extern "C" void kernel_launch(void* const* d_in, const int* in_sizes, int n_in,
                              void* d_out, int out_size, void* d_ws, size_t ws_size,
                              hipStream_t stream) {
    const float* z0  = (const float*)d_in[0];
    const float* t   = (const float*)d_in[1];
    const float* W1  = (const float*)d_in[2];
    const float* b1  = (const float*)d_in[3];
    const float* W2  = (const float*)d_in[4];
    const float* b2  = (const float*)d_in[5];
    const float* Wk1 = (const float*)d_in[6];
    const float* bk1 = (const float*)d_in[7];
    const float* Wk2 = (const float*)d_in[8];
    const float* bk2 = (const float*)d_in[9];
    float* out = (float*)d_out;

    float* ws   = (float*)d_ws;
    float* A    = ws;                       // T*T*HK   = 2,097,152
    float* Wk2t = A    + (size_t)TT*TT*HK;  // HK*D*D   =   524,288
    float* M    = Wk2t + (size_t)HK*DD*DD;  // T*HK*D   = 1,048,576
    float* bF   = M    + (size_t)TT*HK*DD;  // T*D
    float* G    = bF   + TT*DD;             // T*D
    float* P    = G    + TT*DD;             // NCHUNK*T*D = 524,288

    // 1: A + Wk2t
    k_prep<<<1280, 256, 0, stream>>>(t, Wk1, bk1, Wk2, A, Wk2t);

    // 2-9: three iterations; final iteration skips k_Gfin
    for (int it = 0; it < 3; ++it) {
        k_FM<<<dim3(32, 16), 256, 0, stream>>>(G, z0, t, W1, b1, W2, b2,
                                               bk2, Wk2t, M, bF, it);
        k_G1<<<dim3(16, NCHUNK), 256, 0, stream>>>(A, M, P);
        if (it < 2)
            k_Gfin<<<TT, 256, 0, stream>>>(P, bF, t, G);
    }
    // 10: out directly from P + bF
    k_outP<<<1, 256, 0, stream>>>(P, bF, z0, t, out);
}

// Round 9
// 201.459 us; speedup vs baseline: 3.1260x; 1.5471x over previous
//
#include <hip/hip_runtime.h>
#include <hip/hip_bf16.h>

// Problem constants (from reference)
#define TT 128   // time points
#define DD 64    // state dim
#define HH 256   // f-net hidden
#define HK 128   // kernel-net hidden
#define JH (TT*HK)      // 16384 contraction dim
#define HD (HK*DD)      // 8192
#define NCHUNK 64       // jh chunks of 256 (= 2 j's each)

// ---------------------------------------------------------------------------
// k_F (r4-proven): block j: y_j = z0 + dt*trap(G[0..j]) (z0 if it==0),
// then F[j] = tanh(y@W1+b1)@W2+b2, bF[j,d] = sum_e bk2[d*DD+e]*F[j,e]
// ---------------------------------------------------------------------------
__global__ void __launch_bounds__(256)
k_F(const float* __restrict__ G, const float* __restrict__ z0,
    const float* __restrict__ t,
    const float* __restrict__ W1, const float* __restrict__ b1,
    const float* __restrict__ W2, const float* __restrict__ b2,
    const float* __restrict__ bk2,
    float* __restrict__ F, float* __restrict__ bF, int it) {
    int j = blockIdx.x, tid = threadIdx.x;
    int part = tid >> 6, d = tid & 63;
    __shared__ float red[4][64];
    __shared__ float ys[DD];
    __shared__ float hs[HH];
    __shared__ float fs[DD];
    float dt = t[1] - t[0];
    if (it == 0) {
        if (tid < DD) ys[tid] = z0[tid];
    } else {
        float s = 0.f;
        if (j > 0) {
            for (int jp = part; jp <= j; jp += 4) {
                float w = (jp == 0 || jp == j) ? 0.5f : 1.0f;
                s += w * G[jp * DD + d];
            }
        }
        red[part][d] = s;
        __syncthreads();
        if (part == 0)
            ys[d] = z0[d] + dt * (red[0][d] + red[1][d] + red[2][d] + red[3][d]);
    }
    __syncthreads();
    float acc = b1[tid];
    #pragma unroll 8
    for (int e = 0; e < DD; ++e) acc += ys[e] * W1[e * HH + tid];
    hs[tid] = tanhf(acc);
    __syncthreads();
    {
        float s = 0.f;
        #pragma unroll 8
        for (int h = part * 64; h < part * 64 + 64; ++h) s += hs[h] * W2[h * DD + d];
        red[part][d] = s;
    }
    __syncthreads();
    if (part == 0) {
        float a = b2[d] + red[0][d] + red[1][d] + red[2][d] + red[3][d];
        fs[d] = a;
        F[j * DD + d] = a;
    }
    __syncthreads();
    {
        float s = 0.f;
        #pragma unroll
        for (int e = part * 16; e < part * 16 + 16; ++e) s += bk2[d * DD + e] * fs[e];
        red[part][d] = s;
    }
    __syncthreads();
    if (part == 0)
        bF[j * DD + d] = red[0][d] + red[1][d] + red[2][d] + red[3][d];
}

// ---------------------------------------------------------------------------
// k_M: M[j*HD + hd] = sum_e F[j,e] * Wk2[h, d*DD + e]  (hd = h*DD + d)
// Direct Wk2 reads: thread (h,d) loads the CONTIGUOUS row Wk2[h][d*64..+64]
// as float4 pairs — no transpose buffer, no prep kernel.
// grid: (32 hd-chunks of 256, 16 j-chunks of 8), 256 threads, acc[8]
// ---------------------------------------------------------------------------
__global__ void __launch_bounds__(256)
k_M(const float* __restrict__ F, const float* __restrict__ Wk2,
    float* __restrict__ M) {
    int tid = threadIdx.x;
    int hd = blockIdx.x * 256 + tid;
    int j0 = blockIdx.y * 8;
    __shared__ __attribute__((aligned(16))) float Fs[8][64];
    for (int k = tid; k < 8 * DD; k += 256) Fs[k >> 6][k & 63] = F[j0 * DD + k];
    __syncthreads();
    float acc[8] = {0.f,0.f,0.f,0.f,0.f,0.f,0.f,0.f};
    const float* Wrow = Wk2 + (size_t)(hd >> 6) * (DD * DD) + (size_t)(hd & 63) * DD;
    for (int e = 0; e < DD; e += 8) {
        float4 wa = *(const float4*)(Wrow + e);
        float4 wb = *(const float4*)(Wrow + e + 4);
        #pragma unroll
        for (int r = 0; r < 8; ++r) {
            float4 f0 = *(const float4*)&Fs[r][e];
            float4 f1 = *(const float4*)&Fs[r][e + 4];
            acc[r] += f0.x*wa.x + f0.y*wa.y + f0.z*wa.z + f0.w*wa.w
                    + f1.x*wb.x + f1.y*wb.y + f1.z*wb.z + f1.w*wb.w;
        }
    }
    #pragma unroll
    for (int r = 0; r < 8; ++r) M[(size_t)(j0 + r) * HD + hd] = acc[r];
}

// ---------------------------------------------------------------------------
// k_G1 (r4 geometry + on-the-fly A): P[c,i,d] = sum_{jh in chunk c} A[i,jh]*M[jh,d]
// grid: (16 itiles of 8 rows, 64 chunks); active iff c <= 4*itile+3 (544 blocks).
// A computed in-kernel: thread tid has fixed h = tid&127, j = 2c+(tid>>7);
// 8 tanh per thread (~200 cyc) replaces the 8MB A buffer and the prep kernel.
// Final iteration: block (0,0) seeds out = z0 (consumed by k_Gfin's atomics
// after the launch boundary).
// ---------------------------------------------------------------------------
__global__ void __launch_bounds__(256)
k_G1(const float* __restrict__ t, const float* __restrict__ Wk1,
     const float* __restrict__ bk1, const float* __restrict__ M,
     float* __restrict__ P, const float* __restrict__ z0,
     float* __restrict__ out, int final_it) {
    int itile = blockIdx.x, c = blockIdx.y;
    if (c > 4 * itile + 3) return;
    __shared__ __attribute__((aligned(16))) float As[8 * 256];   // 8 KB
    __shared__ float red[4][8][64];                              // 8 KB
    int tid = threadIdx.x, sub = tid >> 6, d = tid & 63;

    {
        float dt = t[1] - t[0];
        int h = tid & 127;
        int j = 2 * c + (tid >> 7);
        float wk0 = Wk1[h], wk1v = Wk1[HK + h], bk = bk1[h];
        float tj = t[j];
        #pragma unroll
        for (int k = 0; k < 8; ++k) {
            int i = itile * 8 + k;
            float w = (i == 0 || j > i) ? 0.f : dt * ((j == 0 || j == i) ? 0.5f : 1.0f);
            As[k * 256 + tid] = w * tanhf(t[i] * wk0 + tj * wk1v + bk);
        }
    }
    if (final_it && itile == 0 && c == 0 && tid < DD) out[tid] = z0[tid];
    __syncthreads();

    float acc[8] = {0.f,0.f,0.f,0.f,0.f,0.f,0.f,0.f};
    const float* Mp = M + ((size_t)c * 256) * DD + d;
    int jl0 = sub * 64;
    for (int jl = jl0; jl < jl0 + 64; jl += 8) {
        float m0 = Mp[(size_t)(jl + 0) * DD];
        float m1 = Mp[(size_t)(jl + 1) * DD];
        float m2 = Mp[(size_t)(jl + 2) * DD];
        float m3 = Mp[(size_t)(jl + 3) * DD];
        float m4 = Mp[(size_t)(jl + 4) * DD];
        float m5 = Mp[(size_t)(jl + 5) * DD];
        float m6 = Mp[(size_t)(jl + 6) * DD];
        float m7 = Mp[(size_t)(jl + 7) * DD];
        #pragma unroll
        for (int r = 0; r < 8; ++r) {
            float4 a0 = *(const float4*)&As[r * 256 + jl];
            float4 a1 = *(const float4*)&As[r * 256 + jl + 4];
            acc[r] += a0.x*m0 + a0.y*m1 + a0.z*m2 + a0.w*m3
                    + a1.x*m4 + a1.y*m5 + a1.z*m6 + a1.w*m7;
        }
    }
    #pragma unroll
    for (int r = 0; r < 8; ++r) red[sub][r][d] = acc[r];
    __syncthreads();
    if (sub == 0) {
        #pragma unroll
        for (int r = 0; r < 8; ++r) {
            float v = red[0][r][d] + red[1][r][d] + red[2][r][d] + red[3][r][d];
            P[(size_t)c * (TT * DD) + (itile * 8 + r) * DD + d] = v;
        }
    }
}

// ---------------------------------------------------------------------------
// k_Gfin (r4-proven): G[j,d] = sum_{c<=j>>1} P[c,j,d] + dt*trap(bF[0..j], d).
// Final iteration: also atomicAdd dt*w_j*G[j,d] into out (pre-seeded = z0 by
// the final k_G1) — 8K atomics over 64 addresses (~2 us) replaces k_out.
// ---------------------------------------------------------------------------
__global__ void __launch_bounds__(256)
k_Gfin(const float* __restrict__ P, const float* __restrict__ bF,
       const float* __restrict__ t, float* __restrict__ G,
       float* __restrict__ out, int final_it) {
    int j = blockIdx.x, tid = threadIdx.x;
    int part = tid >> 6, d = tid & 63;
    __shared__ float red[4][64];
    float dt = t[1] - t[0];
    float a = 0.f;
    int cmax = j >> 1;
    for (int c = part; c <= cmax; c += 4) a += P[(size_t)c * (TT * DD) + j * DD + d];
    if (j > 0) {
        float s = 0.f;
        for (int jp = part; jp <= j; jp += 4) {
            float w = (jp == 0 || jp == j) ? 0.5f : 1.0f;
            s += w * bF[jp * DD + d];
        }
        a += dt * s;
    }
    red[part][d] = a;
    __syncthreads();
    if (part == 0) {
        float v = red[0][d] + red[1][d] + red[2][d] + red[3][d];
        G[j * DD + d] = v;
        if (final_it) {
            float wj = (j == 0 || j == TT - 1) ? 0.5f : 1.0f;
            atomicAdd(&out[d], dt * wj * v);
        }
    }
}

extern "C" void kernel_launch(void* const* d_in, const int* in_sizes, int n_in,
                              void* d_out, int out_size, void* d_ws, size_t ws_size,
                              hipStream_t stream) {
    const float* z0  = (const float*)d_in[0];
    const float* t   = (const float*)d_in[1];
    const float* W1  = (const float*)d_in[2];
    const float* b1  = (const float*)d_in[3];
    const float* W2  = (const float*)d_in[4];
    const float* b2  = (const float*)d_in[5];
    const float* Wk1 = (const float*)d_in[6];
    const float* bk1 = (const float*)d_in[7];
    const float* Wk2 = (const float*)d_in[8];
    const float* bk2 = (const float*)d_in[9];
    float* out = (float*)d_out;

    float* ws = (float*)d_ws;
    float* M  = ws;                        // T*HK*D     = 1,048,576
    float* F  = M  + (size_t)TT*HK*DD;     // T*D
    float* bF = F  + TT*DD;                // T*D
    float* G  = bF + TT*DD;                // T*D
    float* P  = G  + TT*DD;                // NCHUNK*T*D = 524,288

    // 12 launches: 3 x (F, M, G1, Gfin); output folded into the final pair.
    for (int it = 0; it < 3; ++it) {
        int fin = (it == 2) ? 1 : 0;
        k_F<<<TT, 256, 0, stream>>>(G, z0, t, W1, b1, W2, b2, bk2, F, bF, it);
        k_M<<<dim3(32, 16), 256, 0, stream>>>(F, Wk2, M);
        k_G1<<<dim3(16, NCHUNK), 256, 0, stream>>>(t, Wk1, bk1, M, P, z0, out, fin);
        k_Gfin<<<TT, 256, 0, stream>>>(P, bF, t, G, out, fin);
    }
}